// Round 1
// baseline (221.193 us; speedup 1.0000x reference)
//
#include <hip/hip_runtime.h>
#include <hip/hip_bf16.h>

// Problem constants (B=8, S=1024, H=1024)
#define SB 8
#define SS 1024
#define SH 1024
#define LN_EPS 1e-5f

typedef unsigned short u16;
typedef __attribute__((ext_vector_type(8))) short bf16x8;   // 8 bf16 in 4 VGPRs
typedef __attribute__((ext_vector_type(4))) float f32x4;

__device__ __forceinline__ u16 f2bf(float f) {
  __hip_bfloat16 h = __float2bfloat16(f);
  return *reinterpret_cast<u16*>(&h);
}

__device__ __forceinline__ void gld16(const void* g, void* l) {
  __builtin_amdgcn_global_load_lds(
      (const __attribute__((address_space(1))) void*)g,
      (__attribute__((address_space(3))) void*)l, 16, 0, 0);
}

// ---------------------------------------------------------------------------
// Kernel 1: LayerNorm over H, cast to bf16.  One block (256 thr) per row.
// ---------------------------------------------------------------------------
__global__ __launch_bounds__(256) void ln_cast(const float* __restrict__ x,
                                               const float* __restrict__ gamma,
                                               const float* __restrict__ beta,
                                               u16* __restrict__ cnb) {
  const int r = blockIdx.x;
  const int t = threadIdx.x;
  const float* xr = x + (size_t)r * SH;
  float4 v = *(const float4*)(xr + 4 * t);

  __shared__ float red[256];
  // mean
  red[t] = v.x + v.y + v.z + v.w;
  __syncthreads();
#pragma unroll
  for (int off = 128; off > 0; off >>= 1) {
    if (t < off) red[t] += red[t + off];
    __syncthreads();
  }
  const float mu = red[0] * (1.0f / SH);
  __syncthreads();
  // var
  float d0 = v.x - mu, d1 = v.y - mu, d2 = v.z - mu, d3 = v.w - mu;
  red[t] = d0 * d0 + d1 * d1 + d2 * d2 + d3 * d3;
  __syncthreads();
#pragma unroll
  for (int off = 128; off > 0; off >>= 1) {
    if (t < off) red[t] += red[t + off];
    __syncthreads();
  }
  const float rstd = rsqrtf(red[0] * (1.0f / SH) + LN_EPS);

  float4 gm = *(const float4*)(gamma + 4 * t);
  float4 bt = *(const float4*)(beta + 4 * t);
  ushort4 o;
  o.x = f2bf(d0 * rstd * gm.x + bt.x);
  o.y = f2bf(d1 * rstd * gm.y + bt.y);
  o.z = f2bf(d2 * rstd * gm.z + bt.z);
  o.w = f2bf(d3 * rstd * gm.w + bt.w);
  *(ushort4*)(cnb + (size_t)r * SH + 4 * t) = o;
}

// ---------------------------------------------------------------------------
// Kernel 2: build BT[n][j] (bf16) = W[j][n];  n<1024 -> Wq, else Wk.
// 32x32 LDS-tiled transpose + cast.  block (32,8), grid (2048/32, 1024/32).
// ---------------------------------------------------------------------------
__global__ void wtrans(const float* __restrict__ Wk, const float* __restrict__ Wq,
                       u16* __restrict__ BT) {
  __shared__ float tile[32][33];
  const int n0 = blockIdx.x * 32;   // output row block (0..2047)
  const int j0 = blockIdx.y * 32;   // output col block (0..1023)
  const int tx = threadIdx.x, ty = threadIdx.y;
  const float* W = (n0 < 1024) ? Wq : Wk;
  const int nb = n0 & 1023;
#pragma unroll
  for (int jj = 0; jj < 4; ++jj) {
    int jl = ty + jj * 8;
    tile[jl][tx] = W[(size_t)(j0 + jl) * SH + nb + tx];   // coalesced over tx
  }
  __syncthreads();
#pragma unroll
  for (int jj = 0; jj < 4; ++jj) {
    int nl = ty + jj * 8;
    BT[(size_t)(n0 + nl) * SH + j0 + tx] = f2bf(tile[tx][nl]);  // coalesced over tx
  }
}

// ---------------------------------------------------------------------------
// Kernel 3: bf16 MFMA GEMM (m97 structure).  C[M=8192][N=2048] f32 =
//   A[M][K=1024] @ BT[N][K]^T.  128x128 tile, BK=32, 4 waves, 4x4 16x16x32
//   frags/wave, global_load_lds width 16.
// ---------------------------------------------------------------------------
#define BM 128
#define BN 128
#define BK 32
#define GK 1024
#define GN 2048

__global__ __launch_bounds__(256) void gemm_bt(const u16* __restrict__ A,
                                               const u16* __restrict__ Bt,
                                               float* __restrict__ C) {
  __shared__ u16 As[BM * BK];
  __shared__ u16 Bs[BN * BK];
  const int tid = threadIdx.x;
  const int m0 = blockIdx.y * BM;
  const int n0 = blockIdx.x * BN;
  const int wave = tid >> 6, lane = tid & 63;
  const int wm = (wave & 1) * 64, wn = (wave >> 1) * 64;
  const int l15 = lane & 15, q = lane >> 4;

  f32x4 acc[4][4] = {};

  // staging addresses: thread t covers LDS bytes [16t,16t+16) of each 64-row
  // half-tile -> row t/4, k-offset 8*(t&3).  Wave-contiguous (required).
  const int srow = tid >> 2;
  const int scol = 8 * (tid & 3);
  const u16* gA = A + (size_t)(m0 + srow) * GK + scol;
  const u16* gB = Bt + (size_t)(n0 + srow) * GK + scol;
  u16* lA = &As[srow * BK + scol];
  u16* lB = &Bs[srow * BK + scol];

  for (int k0 = 0; k0 < GK; k0 += BK) {
    __syncthreads();  // previous iter's LDS reads done before overwrite
    gld16(gA + k0, lA);
    gld16(gA + (size_t)64 * GK + k0, lA + 64 * BK);
    gld16(gB + k0, lB);
    gld16(gB + (size_t)64 * GK + k0, lB + 64 * BK);
    __syncthreads();  // drains vmcnt(0): tiles visible to all waves

    bf16x8 af[4], bf[4];
#pragma unroll
    for (int fm = 0; fm < 4; ++fm)
      af[fm] = *(const bf16x8*)&As[(wm + fm * 16 + l15) * BK + q * 8];
#pragma unroll
    for (int fn = 0; fn < 4; ++fn)
      bf[fn] = *(const bf16x8*)&Bs[(wn + fn * 16 + l15) * BK + q * 8];
#pragma unroll
    for (int fm = 0; fm < 4; ++fm)
#pragma unroll
      for (int fn = 0; fn < 4; ++fn)
        acc[fm][fn] = __builtin_amdgcn_mfma_f32_16x16x32_bf16(
            af[fm], bf[fn], acc[fm][fn], 0, 0, 0);
  }

  // epilogue: C/D layout col=lane&15, row=(lane>>4)*4+reg  [m89-verified]
#pragma unroll
  for (int fm = 0; fm < 4; ++fm)
#pragma unroll
    for (int fn = 0; fn < 4; ++fn) {
      const int row0 = m0 + wm + fm * 16 + q * 4;
      const int col = n0 + wn + fn * 16 + l15;
#pragma unroll
      for (int r = 0; r < 4; ++r)
        C[(size_t)(row0 + r) * GN + col] = acc[fm][fn][r];
    }
}

// ---------------------------------------------------------------------------
// Kernel 4: adjacent dots + 2-entry softmax.  One wave per row r=b*S+s.
//   d_up = (q[s]+bq)·(k[s+1]+bk), d_dn = (q[s]+bq)·(k[s-1]+bk), scaled 1/32.
// ---------------------------------------------------------------------------
__global__ __launch_bounds__(256) void adj_dots(const float* __restrict__ C,
                                                const float* __restrict__ bq,
                                                const float* __restrict__ bk,
                                                float* __restrict__ pup,
                                                float* __restrict__ pdn) {
  const int wave = threadIdx.x >> 6;
  const int lane = threadIdx.x & 63;
  const int r = blockIdx.x * 4 + wave;
  const int s = r & (SS - 1);
  const bool has_up = (s < SS - 1), has_dn = (s > 0);
  const float* qp = C + (size_t)r * GN;
  const float* kup = C + (size_t)(has_up ? r + 1 : r) * GN + SH;
  const float* kdn = C + (size_t)(has_dn ? r - 1 : r) * GN + SH;

  float du = 0.f, dd = 0.f;
#pragma unroll
  for (int v = 0; v < 4; ++v) {
    const int j = v * 256 + lane * 4;   // coalesced float4 per wave
    float4 qv = *(const float4*)(qp + j);
    float4 bqv = *(const float4*)(bq + j);
    float4 bkv = *(const float4*)(bk + j);
    const float a0 = qv.x + bqv.x, a1 = qv.y + bqv.y;
    const float a2 = qv.z + bqv.z, a3 = qv.w + bqv.w;
    if (has_up) {
      float4 ku = *(const float4*)(kup + j);
      du += a0 * (ku.x + bkv.x) + a1 * (ku.y + bkv.y) + a2 * (ku.z + bkv.z) +
            a3 * (ku.w + bkv.w);
    }
    if (has_dn) {
      float4 kd = *(const float4*)(kdn + j);
      dd += a0 * (kd.x + bkv.x) + a1 * (kd.y + bkv.y) + a2 * (kd.z + bkv.z) +
            a3 * (kd.w + bkv.w);
    }
  }
#pragma unroll
  for (int off = 32; off > 0; off >>= 1) {
    du += __shfl_down(du, off, 64);
    dd += __shfl_down(dd, off, 64);
  }
  if (lane == 0) {
    const float scale = 0.03125f;  // 1/sqrt(1024)
    du *= scale;
    dd *= scale;
    float pu, pd;
    if (!has_dn) { pu = 1.f; pd = 0.f; }
    else if (!has_up) { pu = 0.f; pd = 1.f; }
    else {
      const float m = fmaxf(du, dd);
      const float eu = __expf(du - m), ed = __expf(dd - m);
      const float inv = 1.f / (eu + ed);
      pu = eu * inv;
      pd = ed * inv;
    }
    pup[r] = pu;
    pdn[r] = pd;
  }
}

// ---------------------------------------------------------------------------
// Kernel 5: fused elementwise + rowsum + outputs.  One block per row (b,i).
//   nb(i,k) = sqrt(1e-9) except k=i±1 where sqrt(p_up*p_dn'+1e-9)
//   ne = prior + (1-prior)*nb                       -> output neibor
//   gt = (k==i)? 2+1e-9 : 1+ne ; g = gt/(sum+1e-9)  -> output g
//   (the hierarchical prefix product cancels: keep-mask zeroes exp region)
// ---------------------------------------------------------------------------
__global__ __launch_bounds__(256) void rows_kernel(const float* __restrict__ prior,
                                                   const int* __restrict__ mask,
                                                   const float* __restrict__ pup,
                                                   const float* __restrict__ pdn,
                                                   float* __restrict__ g_out,
                                                   float* __restrict__ ne_out) {
  const int r = blockIdx.x;
  const int b = r >> 10, i = r & (SS - 1);
  const int t = threadIdx.x;
  const float nbz = 3.1622776601683795e-5f;  // sqrt(1e-9)
  const float nb_im1 = (i >= 1) ? sqrtf(pup[r - 1] * pdn[r] + 1e-9f) : nbz;
  const float nb_ip1 = (i <= SS - 2) ? sqrtf(pup[r] * pdn[r + 1] + 1e-9f) : nbz;

  const float* prow = prior + (size_t)r * SS;
  float4 pr = *(const float4*)(prow + 4 * t);
  const int* mrow = mask + b * SS;
  const float padi = (mrow[i] != 0) ? 1.f : 0.f;
  int4 mk = *(const int4*)(mrow + 4 * t);

  float ne[4], gsum = 0.f;
#pragma unroll
  for (int v = 0; v < 4; ++v) {
    const int k = 4 * t + v;
    const float p = (&pr.x)[v];
    const float nb = (k == i - 1) ? nb_im1 : (k == i + 1) ? nb_ip1 : nbz;
    const float n = p + (1.f - p) * nb;
    ne[v] = n;
    gsum += (k == i) ? (2.f + 1e-9f) : (1.f + n);
  }

  __shared__ float red[256];
  red[t] = gsum;
  __syncthreads();
#pragma unroll
  for (int off = 128; off > 0; off >>= 1) {
    if (t < off) red[t] += red[t + off];
    __syncthreads();
  }
  const float inv = 1.f / (red[0] + 1e-9f);

  float4 go, no;
#pragma unroll
  for (int v = 0; v < 4; ++v) {
    const int k = 4 * t + v;
    const float padk = ((&mk.x)[v] != 0) ? 1.f : 0.f;
    const float f2 = padi * padk;
    const float gt = (k == i) ? (2.f + 1e-9f) : (1.f + ne[v]);
    (&go.x)[v] = gt * inv * f2;
    (&no.x)[v] = ne[v] * f2;
  }
  *(float4*)(g_out + (size_t)r * SS + 4 * t) = go;
  *(float4*)(ne_out + (size_t)r * SS + 4 * t) = no;
}

// ---------------------------------------------------------------------------
extern "C" void kernel_launch(void* const* d_in, const int* in_sizes, int n_in,
                              void* d_out, int out_size, void* d_ws, size_t ws_size,
                              hipStream_t stream) {
  const float* context = (const float*)d_in[0];
  const int* mask = (const int*)d_in[1];
  const float* prior = (const float*)d_in[2];
  const float* gamma = (const float*)d_in[3];
  const float* beta = (const float*)d_in[4];
  const float* Wk = (const float*)d_in[5];
  const float* bk = (const float*)d_in[6];
  const float* Wq = (const float*)d_in[7];
  const float* bq = (const float*)d_in[8];

  float* out_g = (float*)d_out;
  float* out_n = out_g + (size_t)SB * SS * SS;

  char* ws = (char*)d_ws;
  u16* cnb = (u16*)ws;                                   // 16 MB  bf16 [8192,1024]
  u16* BT = (u16*)(ws + ((size_t)16 << 20));             // 4 MB   bf16 [2048,1024]
  float* Cqk = (float*)(ws + ((size_t)20 << 20));        // 64 MB  f32  [8192,2048]
  float* pup = (float*)(ws + ((size_t)84 << 20));        // 32 KB
  float* pdn = (float*)(ws + ((size_t)84 << 20) + 8192 * sizeof(float));

  ln_cast<<<SB * SS, 256, 0, stream>>>(context, gamma, beta, cnb);
  wtrans<<<dim3(GN / 32, SH / 32), dim3(32, 8), 0, stream>>>(Wk, Wq, BT);
  gemm_bt<<<dim3(GN / BN, SB * SS / BM), 256, 0, stream>>>(cnb, BT, Cqk);
  adj_dots<<<SB * SS / 4, 256, 0, stream>>>(Cqk, bq, bk, pup, pdn);
  rows_kernel<<<SB * SS, 256, 0, stream>>>(prior, mask, pup, pdn, out_g, out_n);
}

// Round 2
// 209.135 us; speedup vs baseline: 1.0577x; 1.0577x over previous
//
#include <hip/hip_runtime.h>
#include <hip/hip_bf16.h>

// Problem constants (B=8, S=1024, H=1024)
#define SB 8
#define SS 1024
#define SH 1024
#define LN_EPS 1e-5f

typedef unsigned short u16;
typedef __attribute__((ext_vector_type(8))) short bf16x8;   // 8 bf16 in 4 VGPRs
typedef __attribute__((ext_vector_type(4))) float f32x4;

__device__ __forceinline__ u16 f2bf(float f) {
  __hip_bfloat16 h = __float2bfloat16(f);
  return *reinterpret_cast<u16*>(&h);
}
__device__ __forceinline__ float bf2f(u16 x) {
  unsigned v = ((unsigned)x) << 16;
  return __builtin_bit_cast(float, v);
}

__device__ __forceinline__ void gld16(const void* g, void* l) {
  __builtin_amdgcn_global_load_lds(
      (const __attribute__((address_space(1))) void*)g,
      (__attribute__((address_space(3))) void*)l, 16, 0, 0);
}

// ---------------------------------------------------------------------------
// Kernel 1: LayerNorm over H, cast to bf16.  One block (256 thr) per row.
// Wave-shuffle reduction + 4-way LDS combine (2 barriers total).
// ---------------------------------------------------------------------------
__global__ __launch_bounds__(256) void ln_cast(const float* __restrict__ x,
                                               const float* __restrict__ gamma,
                                               const float* __restrict__ beta,
                                               u16* __restrict__ cnb) {
  const int r = blockIdx.x;
  const int t = threadIdx.x;
  const int wave = t >> 6, lane = t & 63;
  const float* xr = x + (size_t)r * SH;
  float4 v = *(const float4*)(xr + 4 * t);

  __shared__ float p1[4], p2[4];
  float s = v.x + v.y + v.z + v.w;
#pragma unroll
  for (int off = 32; off > 0; off >>= 1) s += __shfl_down(s, off, 64);
  if (lane == 0) p1[wave] = s;
  __syncthreads();
  const float mu = (p1[0] + p1[1] + p1[2] + p1[3]) * (1.0f / SH);

  float d0 = v.x - mu, d1 = v.y - mu, d2 = v.z - mu, d3 = v.w - mu;
  float ss = d0 * d0 + d1 * d1 + d2 * d2 + d3 * d3;
#pragma unroll
  for (int off = 32; off > 0; off >>= 1) ss += __shfl_down(ss, off, 64);
  if (lane == 0) p2[wave] = ss;
  __syncthreads();
  const float rstd = rsqrtf((p2[0] + p2[1] + p2[2] + p2[3]) * (1.0f / SH) + LN_EPS);

  float4 gm = *(const float4*)(gamma + 4 * t);
  float4 bt = *(const float4*)(beta + 4 * t);
  ushort4 o;
  o.x = f2bf(d0 * rstd * gm.x + bt.x);
  o.y = f2bf(d1 * rstd * gm.y + bt.y);
  o.z = f2bf(d2 * rstd * gm.z + bt.z);
  o.w = f2bf(d3 * rstd * gm.w + bt.w);
  *(ushort4*)(cnb + (size_t)r * SH + 4 * t) = o;
}

// ---------------------------------------------------------------------------
// Kernel 2: cast Wq, Wk (f32) to bf16 (row-major, no transpose needed — the
// NT GEMM contracts along the fast dim of both operands).
// ---------------------------------------------------------------------------
__global__ __launch_bounds__(256) void wcast(const float* __restrict__ Wq,
                                             const float* __restrict__ Wk,
                                             u16* __restrict__ Wq_bf,
                                             u16* __restrict__ Wk_bf) {
  const size_t e = ((size_t)blockIdx.x * 256 + threadIdx.x) * 4;
  const size_t M = (size_t)SH * SH;
  const float* src;
  u16* dst;
  if (e < M) { src = Wq + e; dst = Wq_bf + e; }
  else       { src = Wk + (e - M); dst = Wk_bf + (e - M); }
  float4 v = *(const float4*)src;
  ushort4 o;
  o.x = f2bf(v.x); o.y = f2bf(v.y); o.z = f2bf(v.z); o.w = f2bf(v.w);
  *(ushort4*)dst = o;
}

// ---------------------------------------------------------------------------
// Kernel 3: wkbq[h] = sum_n Wk[h,n] * bq[n]   (only bias term that survives
// softmax shift-invariance: cn[s]·wqbk + bq·bk is common to both entries).
// One wave per h.
// ---------------------------------------------------------------------------
__global__ __launch_bounds__(256) void wkbq_kernel(const float* __restrict__ Wk,
                                                   const float* __restrict__ bq,
                                                   float* __restrict__ wkbq) {
  const int wave = threadIdx.x >> 6, lane = threadIdx.x & 63;
  const int h = blockIdx.x * 4 + wave;
  const float* row = Wk + (size_t)h * SH;
  float s = 0.f;
#pragma unroll
  for (int v = 0; v < 4; ++v) {
    const int j = v * 256 + lane * 4;
    float4 w = *(const float4*)(row + j);
    float4 b = *(const float4*)(bq + j);
    s += w.x * b.x + w.y * b.y + w.z * b.z + w.w * b.w;
  }
#pragma unroll
  for (int off = 32; off > 0; off >>= 1) s += __shfl_down(s, off, 64);
  if (lane == 0) wkbq[h] = s;
}

// ---------------------------------------------------------------------------
// Kernel 4: bf16 MFMA GEMM (m97 structure), templated.
//   C[M][GNv] = A[M][GKv] @ Bt[GNv][GKv]^T.  128x128 tile, BK=32, 4 waves,
//   4x4 16x16x32 frags/wave, global_load_lds width 16.  Optional bf16 out.
// ---------------------------------------------------------------------------
#define BM 128
#define BN 128
#define BK 32

template <int GKv, int GNv, bool BF16OUT>
__global__ __launch_bounds__(256) void gemm_bt_t(const u16* __restrict__ A,
                                                 const u16* __restrict__ Bt,
                                                 void* __restrict__ Cv) {
  __shared__ u16 As[BM * BK];
  __shared__ u16 Bs[BN * BK];
  const int tid = threadIdx.x;
  const int m0 = blockIdx.y * BM;
  const int n0 = blockIdx.x * BN;
  const int wave = tid >> 6, lane = tid & 63;
  const int wm = (wave & 1) * 64, wn = (wave >> 1) * 64;
  const int l15 = lane & 15, q = lane >> 4;

  f32x4 acc[4][4] = {};

  const int srow = tid >> 2;
  const int scol = 8 * (tid & 3);
  const u16* gA = A + (size_t)(m0 + srow) * GKv + scol;
  const u16* gB = Bt + (size_t)(n0 + srow) * GKv + scol;
  u16* lA = &As[srow * BK + scol];
  u16* lB = &Bs[srow * BK + scol];

  for (int k0 = 0; k0 < GKv; k0 += BK) {
    __syncthreads();
    gld16(gA + k0, lA);
    gld16(gA + (size_t)64 * GKv + k0, lA + 64 * BK);
    gld16(gB + k0, lB);
    gld16(gB + (size_t)64 * GKv + k0, lB + 64 * BK);
    __syncthreads();

    bf16x8 af[4], bfr[4];
#pragma unroll
    for (int fm = 0; fm < 4; ++fm)
      af[fm] = *(const bf16x8*)&As[(wm + fm * 16 + l15) * BK + q * 8];
#pragma unroll
    for (int fn = 0; fn < 4; ++fn)
      bfr[fn] = *(const bf16x8*)&Bs[(wn + fn * 16 + l15) * BK + q * 8];
#pragma unroll
    for (int fm = 0; fm < 4; ++fm)
#pragma unroll
      for (int fn = 0; fn < 4; ++fn)
        acc[fm][fn] = __builtin_amdgcn_mfma_f32_16x16x32_bf16(
            af[fm], bfr[fn], acc[fm][fn], 0, 0, 0);
  }

  // C/D layout: col=lane&15, row=(lane>>4)*4+reg  [m89-verified]
#pragma unroll
  for (int fm = 0; fm < 4; ++fm)
#pragma unroll
    for (int fn = 0; fn < 4; ++fn) {
      const int row0 = m0 + wm + fm * 16 + q * 4;
      const int col = n0 + wn + fn * 16 + l15;
#pragma unroll
      for (int r = 0; r < 4; ++r) {
        const size_t idx = (size_t)(row0 + r) * GNv + col;
        if (BF16OUT) ((u16*)Cv)[idx] = f2bf(acc[fm][fn][r]);
        else ((float*)Cv)[idx] = acc[fm][fn][r];
      }
    }
}

// ---------------------------------------------------------------------------
// Kernel 5: adjacent bilinear dots + 2-entry softmax.  One wave per row r.
//   du = (u[r] + wkbq) · cn[r+1],  dd = (u[r] + wkbq) · cn[r-1], scaled 1/32.
// ---------------------------------------------------------------------------
__global__ __launch_bounds__(256) void adj_dots(const float* __restrict__ U,
                                                const u16* __restrict__ cnb,
                                                const float* __restrict__ wkbq,
                                                float* __restrict__ pup,
                                                float* __restrict__ pdn) {
  const int wave = threadIdx.x >> 6;
  const int lane = threadIdx.x & 63;
  const int r = blockIdx.x * 4 + wave;
  const int s = r & (SS - 1);
  const bool has_up = (s < SS - 1), has_dn = (s > 0);
  const float* ur = U + (size_t)r * SH;
  const u16* up = cnb + (size_t)(has_up ? r + 1 : r) * SH;
  const u16* dn = cnb + (size_t)(has_dn ? r - 1 : r) * SH;

  float du = 0.f, dd = 0.f;
#pragma unroll
  for (int v = 0; v < 4; ++v) {
    const int j = v * 256 + lane * 4;
    float4 uv = *(const float4*)(ur + j);
    float4 wv = *(const float4*)(wkbq + j);
    ushort4 us = *(const ushort4*)(up + j);
    ushort4 ds = *(const ushort4*)(dn + j);
    const float t0 = uv.x + wv.x, t1 = uv.y + wv.y;
    const float t2 = uv.z + wv.z, t3 = uv.w + wv.w;
    du += bf2f(us.x) * t0 + bf2f(us.y) * t1 + bf2f(us.z) * t2 + bf2f(us.w) * t3;
    dd += bf2f(ds.x) * t0 + bf2f(ds.y) * t1 + bf2f(ds.z) * t2 + bf2f(ds.w) * t3;
  }
#pragma unroll
  for (int off = 32; off > 0; off >>= 1) {
    du += __shfl_down(du, off, 64);
    dd += __shfl_down(dd, off, 64);
  }
  if (lane == 0) {
    const float scale = 0.03125f;  // 1/sqrt(1024)
    du *= scale;
    dd *= scale;
    float pu, pd;
    if (!has_dn) { pu = 1.f; pd = 0.f; }
    else if (!has_up) { pu = 0.f; pd = 1.f; }
    else {
      const float m = fmaxf(du, dd);
      const float eu = __expf(du - m), ed = __expf(dd - m);
      const float inv = 1.f / (eu + ed);
      pu = eu * inv;
      pd = ed * inv;
    }
    pup[r] = pu;
    pdn[r] = pd;
  }
}

// ---------------------------------------------------------------------------
// Kernel 6: fused elementwise + rowsum + outputs.  One block per row (b,i).
//   (hierarchical prefix product cancels: g + g^T = 1 + eye off the stored
//   diag, so gt = (k==i)? 2+1e-9 : 1+ne, row-normalized.)
// ---------------------------------------------------------------------------
__global__ __launch_bounds__(256) void rows_kernel(const float* __restrict__ prior,
                                                   const int* __restrict__ mask,
                                                   const float* __restrict__ pup,
                                                   const float* __restrict__ pdn,
                                                   float* __restrict__ g_out,
                                                   float* __restrict__ ne_out) {
  const int r = blockIdx.x;
  const int b = r >> 10, i = r & (SS - 1);
  const int t = threadIdx.x;
  const int wave = t >> 6, lane = t & 63;
  const float nbz = 3.1622776601683795e-5f;  // sqrt(1e-9)
  const float nb_im1 = (i >= 1) ? sqrtf(pup[r - 1] * pdn[r] + 1e-9f) : nbz;
  const float nb_ip1 = (i <= SS - 2) ? sqrtf(pup[r] * pdn[r + 1] + 1e-9f) : nbz;

  const float* prow = prior + (size_t)r * SS;
  float4 pr = *(const float4*)(prow + 4 * t);
  const int* mrow = mask + b * SS;
  const float padi = (mrow[i] != 0) ? 1.f : 0.f;
  int4 mk = *(const int4*)(mrow + 4 * t);

  float ne[4], gsum = 0.f;
#pragma unroll
  for (int v = 0; v < 4; ++v) {
    const int k = 4 * t + v;
    const float p = (&pr.x)[v];
    const float nb = (k == i - 1) ? nb_im1 : (k == i + 1) ? nb_ip1 : nbz;
    const float n = p + (1.f - p) * nb;
    ne[v] = n;
    gsum += (k == i) ? (2.f + 1e-9f) : (1.f + n);
  }

  __shared__ float part[4];
#pragma unroll
  for (int off = 32; off > 0; off >>= 1) gsum += __shfl_down(gsum, off, 64);
  if (lane == 0) part[wave] = gsum;
  __syncthreads();
  const float inv = 1.f / (part[0] + part[1] + part[2] + part[3] + 1e-9f);

  float4 go, no;
#pragma unroll
  for (int v = 0; v < 4; ++v) {
    const int k = 4 * t + v;
    const float padk = ((&mk.x)[v] != 0) ? 1.f : 0.f;
    const float f2 = padi * padk;
    const float gt = (k == i) ? (2.f + 1e-9f) : (1.f + ne[v]);
    (&go.x)[v] = gt * inv * f2;
    (&no.x)[v] = ne[v] * f2;
  }
  *(float4*)(g_out + (size_t)r * SS + 4 * t) = go;
  *(float4*)(ne_out + (size_t)r * SS + 4 * t) = no;
}

// ---------------------------------------------------------------------------
extern "C" void kernel_launch(void* const* d_in, const int* in_sizes, int n_in,
                              void* d_out, int out_size, void* d_ws, size_t ws_size,
                              hipStream_t stream) {
  const float* context = (const float*)d_in[0];
  const int* mask = (const int*)d_in[1];
  const float* prior = (const float*)d_in[2];
  const float* gamma = (const float*)d_in[3];
  const float* beta = (const float*)d_in[4];
  const float* Wk = (const float*)d_in[5];
  const float* bk = (const float*)d_in[6];  // unused: cancels in softmax shift
  const float* Wq = (const float*)d_in[7];
  const float* bq = (const float*)d_in[8];
  (void)bk;

  float* out_g = (float*)d_out;
  float* out_n = out_g + (size_t)SB * SS * SS;

  char* ws = (char*)d_ws;
  u16* cnb = (u16*)ws;                                   // 16 MB  bf16 [8192,1024]
  u16* Wq_bf = (u16*)(ws + ((size_t)16 << 20));          // 2 MB
  u16* Wk_bf = (u16*)(ws + ((size_t)18 << 20));          // 2 MB
  u16* PT = (u16*)(ws + ((size_t)20 << 20));             // 2 MB  bf16 [1024,1024] = (WqWk^T)^T
  float* U = (float*)(ws + ((size_t)24 << 20));          // 32 MB f32  [8192,1024] = cn @ P
  float* wkbq = (float*)(ws + ((size_t)56 << 20));       // 4 KB
  float* pup = (float*)(ws + ((size_t)57 << 20));        // 32 KB
  float* pdn = (float*)(ws + ((size_t)57 << 20) + 8192 * sizeof(float));

  ln_cast<<<SB * SS, 256, 0, stream>>>(context, gamma, beta, cnb);
  wcast<<<2048, 256, 0, stream>>>(Wq, Wk, Wq_bf, Wk_bf);
  wkbq_kernel<<<256, 256, 0, stream>>>(Wk, bq, wkbq);
  // PT[h',h] = sum_m Wk[h',m] Wq[h,m] = P[h,h'] — exactly Bt layout for ugemm
  gemm_bt_t<1024, 1024, true><<<dim3(8, 8), 256, 0, stream>>>(Wk_bf, Wq_bf, PT);
  // U[s,h'] = sum_h cn[s,h] P[h,h']
  gemm_bt_t<1024, 1024, false><<<dim3(8, 64), 256, 0, stream>>>(cnb, PT, U);
  adj_dots<<<SB * SS / 4, 256, 0, stream>>>(U, cnb, wkbq, pup, pdn);
  rows_kernel<<<SB * SS, 256, 0, stream>>>(prior, mask, pup, pdn, out_g, out_n);
}